// Round 1
// baseline (538.941 us; speedup 1.0000x reference)
//
#include <hip/hip_runtime.h>
#include <hip/hip_bf16.h>
#include <math.h>

// ---------------------------------------------------------------------------
// GCN forward on MI355X.
// Pipeline:
//   deg -> scan -> CSR fill (by dst, self-loops included)
//   h = x @ W_enc + b_enc
//   2x: hw = (h @ Wc[l]) * dinv[row] ; h = gather-sum(hw[col]) * dinv[i] + bc
//       BN (stats -> scale/shift -> apply+ReLU)
//   pool (sorted batch ranges) -> MLP head -> sigmoid
// All fp32 (no fp32 MFMA on CDNA4 -> vector ALU GEMM with 8-row reg blocking).
// ---------------------------------------------------------------------------

#define WAVE 64

__global__ __launch_bounds__(256) void k_init(int* __restrict__ deg,
                                              float* __restrict__ pooled,
                                              float* __restrict__ bnstat,
                                              int N) {
  int i = blockIdx.x * 256 + threadIdx.x;
  if (i < N) deg[i] = 1;           // self-loop
  if (i < 64 * 128) pooled[i] = 0.f;
  if (i < 512) bnstat[i] = 0.f;    // sum/sumsq for both layers
}

__global__ __launch_bounds__(256) void k_deg(const int* __restrict__ ei, int E,
                                             int* __restrict__ deg) {
  int i = blockIdx.x * 256 + threadIdx.x;
  if (i < E) atomicAdd(&deg[ei[E + i]], 1);   // dst row
}

// ---- 3-kernel exclusive scan over deg[N] -> rowptr ----
__global__ __launch_bounds__(256) void k_scan_a(const int* __restrict__ deg, int N,
                                                int* __restrict__ rowptr,
                                                int* __restrict__ blksum) {
  __shared__ int s[256];
  int t = threadIdx.x;
  int i = blockIdx.x * 256 + t;
  int v = (i < N) ? deg[i] : 0;
  s[t] = v;
  __syncthreads();
  for (int off = 1; off < 256; off <<= 1) {
    int x = (t >= off) ? s[t - off] : 0;
    __syncthreads();
    s[t] += x;
    __syncthreads();
  }
  if (i < N) rowptr[i] = s[t] - v;            // exclusive (partial)
  if (t == 255) blksum[blockIdx.x] = s[255];
}

__global__ __launch_bounds__(256) void k_scan_b(int* __restrict__ blksum, int nb) {
  __shared__ int s[256];
  int t = threadIdx.x;
  int v = (t < nb) ? blksum[t] : 0;
  s[t] = v;
  __syncthreads();
  for (int off = 1; off < 256; off <<= 1) {
    int x = (t >= off) ? s[t - off] : 0;
    __syncthreads();
    s[t] += x;
    __syncthreads();
  }
  if (t < nb) blksum[t] = s[t] - v;           // exclusive
}

__global__ __launch_bounds__(256) void k_scan_c(const int* __restrict__ deg, int N,
                                                int total,
                                                const int* __restrict__ blksum,
                                                int* __restrict__ rowptr,
                                                int* __restrict__ cursor,
                                                float* __restrict__ dinv) {
  int i = blockIdx.x * 256 + threadIdx.x;
  if (i < N) {
    int rp = rowptr[i] + blksum[blockIdx.x];
    rowptr[i] = rp;
    cursor[i] = rp;
    dinv[i] = rsqrtf((float)deg[i]);
  } else if (i == N) {
    rowptr[N] = total;
  }
}

__global__ __launch_bounds__(256) void k_fill(const int* __restrict__ ei, int E, int N,
                                              int* __restrict__ cursor,
                                              int* __restrict__ colx) {
  int i = blockIdx.x * 256 + threadIdx.x;
  if (i < E) {
    int s = ei[i];
    int d = ei[E + i];
    int pos = atomicAdd(&cursor[d], 1);
    colx[pos] = s;
  } else if (i < E + N) {
    int j = i - E;
    int pos = atomicAdd(&cursor[j], 1);
    colx[pos] = j;                           // self-loop entry
  }
}

// ---- GEMM: Y[N][128] = X[N][K] @ W[K][128] (+bias) (*scale[row]) ----
// block=256 (4 waves). W staged in LDS. Each wave: 8 consecutive rows,
// each lane: 2 consecutive columns (float2 LDS reads, 2-way free).
// X rows read via wave-uniform addresses -> scalar loads.
template <int K>
__global__ __launch_bounds__(256) void k_gemm(const float* __restrict__ X,
                                              const float* __restrict__ W,
                                              const float* __restrict__ bias,
                                              const float* __restrict__ scale,
                                              float* __restrict__ Y, int N) {
  __shared__ float Wl[K * 128];
  for (int i = threadIdx.x; i < K * 32; i += 256)   // K*128/4 float4s
    ((float4*)Wl)[i] = ((const float4*)W)[i];
  __syncthreads();

  int lane = threadIdx.x & 63;
  int wv = __builtin_amdgcn_readfirstlane(threadIdx.x >> 6);
  int c0 = 2 * lane;
  int rowBase = blockIdx.x * 32 + wv * 8;

  float2 bb = make_float2(0.f, 0.f);
  if (bias) bb = *(const float2*)&bias[c0];

  const float* xr[8];
#pragma unroll
  for (int r = 0; r < 8; r++) {
    int rr = rowBase + r;
    if (rr > N - 1) rr = N - 1;
    xr[r] = X + (size_t)rr * K;
  }

  float a0[8], a1[8];
#pragma unroll
  for (int r = 0; r < 8; r++) { a0[r] = bb.x; a1[r] = bb.y; }

#pragma unroll 4
  for (int k = 0; k < K; k++) {
    float2 w2 = *(const float2*)&Wl[k * 128 + c0];
#pragma unroll
    for (int r = 0; r < 8; r++) {
      float xv = xr[r][k];
      a0[r] += xv * w2.x;
      a1[r] += xv * w2.y;
    }
  }

#pragma unroll
  for (int r = 0; r < 8; r++) {
    int row = rowBase + r;
    if (row < N) {
      float s = scale ? scale[row] : 1.f;
      float2 o = make_float2(a0[r] * s, a1[r] * s);
      *(float2*)&Y[(size_t)row * 128 + c0] = o;
    }
  }
}

// ---- Aggregate: Y[i] = (sum over CSR row i of HWs[col]) * dinv[i] + bias ----
// HWs rows are pre-scaled by dinv[src] in the GEMM epilogue.
__global__ __launch_bounds__(256) void k_agg(const float* __restrict__ HWs,
                                             const int* __restrict__ rowptr,
                                             const int* __restrict__ colx,
                                             const float* __restrict__ dinv,
                                             const float* __restrict__ bias,
                                             float* __restrict__ Y, int N) {
  int lane = threadIdx.x & 63;
  int wv = __builtin_amdgcn_readfirstlane(threadIdx.x >> 6);
  int wid = blockIdx.x * 4 + wv;
  int nw = gridDim.x * 4;
  int c0 = 2 * lane;
  float2 bb = *(const float2*)&bias[c0];

  for (int i = wid; i < N; i += nw) {
    int beg = rowptr[i];
    int end = rowptr[i + 1];
    float s0 = 0.f, s1 = 0.f;
    for (int e = beg; e < end; e++) {
      int s = colx[e];
      float2 v = *(const float2*)&HWs[(size_t)s * 128 + c0];
      s0 += v.x;
      s1 += v.y;
    }
    float di = dinv[i];
    float2 o = make_float2(s0 * di + bb.x, s1 * di + bb.y);
    *(float2*)&Y[(size_t)i * 128 + c0] = o;
  }
}

// ---- BN ----
__global__ __launch_bounds__(256) void k_bnstat(const float* __restrict__ H, int N,
                                                float* __restrict__ stat) {
  int c = threadIdx.x & 127;
  int half = threadIdx.x >> 7;
  float s = 0.f, q = 0.f;
  for (int r = blockIdx.x * 2 + half; r < N; r += gridDim.x * 2) {
    float v = H[(size_t)r * 128 + c];
    s += v;
    q += v * v;
  }
  __shared__ float ls[256], lq[256];
  ls[threadIdx.x] = s;
  lq[threadIdx.x] = q;
  __syncthreads();
  if (threadIdx.x < 128) {
    atomicAdd(&stat[c], ls[threadIdx.x] + ls[threadIdx.x + 128]);
    atomicAdd(&stat[128 + c], lq[threadIdx.x] + lq[threadIdx.x + 128]);
  }
}

__global__ __launch_bounds__(128) void k_bnfinal(const float* __restrict__ stat,
                                                 const float* __restrict__ gamma,
                                                 const float* __restrict__ beta,
                                                 float invN,
                                                 float* __restrict__ scsh) {
  int c = threadIdx.x;
  float mu = stat[c] * invN;
  float var = stat[128 + c] * invN - mu * mu;
  float sc = rsqrtf(var + 1e-5f) * gamma[c];
  scsh[c] = sc;
  scsh[128 + c] = beta[c] - mu * sc;
}

__global__ __launch_bounds__(256) void k_bnapply(float* __restrict__ H, int n4,
                                                 const float* __restrict__ scsh) {
  const float4* SC4 = (const float4*)scsh;
  const float4* SH4 = (const float4*)(scsh + 128);
  for (int i = blockIdx.x * 256 + threadIdx.x; i < n4; i += gridDim.x * 256) {
    float4 v = ((float4*)H)[i];
    int c4 = i & 31;
    float4 sc = SC4[c4], sh = SH4[c4];
    v.x = fmaxf(fmaf(v.x, sc.x, sh.x), 0.f);
    v.y = fmaxf(fmaf(v.y, sc.y, sh.y), 0.f);
    v.z = fmaxf(fmaf(v.z, sc.z, sh.z), 0.f);
    v.w = fmaxf(fmaf(v.w, sc.w, sh.w), 0.f);
    ((float4*)H)[i] = v;
  }
}

// ---- Pool ----
__global__ __launch_bounds__(128) void k_gstart(const int* __restrict__ batch, int N,
                                                int* __restrict__ gstart) {
  int g = threadIdx.x;
  if (g <= 64) {
    int lo = 0, hi = N;
    while (lo < hi) {
      int mid = (lo + hi) >> 1;
      if (batch[mid] < g) lo = mid + 1;
      else hi = mid;
    }
    gstart[g] = lo;   // lower_bound; gstart[64] == N
  }
}

__global__ __launch_bounds__(128) void k_pool(const float* __restrict__ H,
                                              const int* __restrict__ gstart,
                                              float* __restrict__ pooled) {
  int g = blockIdx.x >> 2;
  int part = blockIdx.x & 3;
  int beg = gstart[g], end = gstart[g + 1];
  int len = end - beg;
  int pbeg = beg + (len * part) / 4;
  int pend = beg + (len * (part + 1)) / 4;
  float s = 0.f;
  for (int r = pbeg; r < pend; r++) s += H[(size_t)r * 128 + threadIdx.x];
  atomicAdd(&pooled[g * 128 + threadIdx.x], s);
}

// ---- Head MLP ----
__global__ __launch_bounds__(256) void k_mlp(const float* __restrict__ pooled,
                                             const int* __restrict__ gstart,
                                             const float* __restrict__ W1,
                                             const float* __restrict__ b1,
                                             const float* __restrict__ W2,
                                             const float* __restrict__ b2,
                                             float* __restrict__ out) {
  __shared__ float P[64 * 128];
  __shared__ float Z[64 * 64];
  for (int i = threadIdx.x; i < 64 * 128; i += 256) {
    int g = i >> 7;
    int cnt = gstart[g + 1] - gstart[g];
    P[i] = pooled[i] / (float)(cnt > 1 ? cnt : 1);
  }
  __syncthreads();
  for (int i = threadIdx.x; i < 64 * 64; i += 256) {
    int g = i >> 6, m = i & 63;
    float acc = b1[m];
    for (int k = 0; k < 128; k++) acc += P[(g << 7) + k] * W1[k * 64 + m];
    Z[i] = fmaxf(acc, 0.f);
  }
  __syncthreads();
  if (threadIdx.x < 64) {
    int g = threadIdx.x;
    float acc = b2[0];
    for (int m = 0; m < 64; m++) acc += Z[(g << 6) + m] * W2[m];
    out[g] = 1.f / (1.f + expf(-acc));
  }
}

// ---------------------------------------------------------------------------

extern "C" void kernel_launch(void* const* d_in, const int* in_sizes, int n_in,
                              void* d_out, int out_size, void* d_ws, size_t ws_size,
                              hipStream_t stream) {
  const float* x      = (const float*)d_in[0];
  const int*   ei     = (const int*)d_in[1];
  const int*   batch  = (const int*)d_in[2];
  const float* W_enc  = (const float*)d_in[3];
  const float* b_enc  = (const float*)d_in[4];
  const float* Wc     = (const float*)d_in[5];
  const float* bc     = (const float*)d_in[6];
  const float* gamma  = (const float*)d_in[7];
  const float* beta   = (const float*)d_in[8];
  const float* W1     = (const float*)d_in[9];
  const float* b1     = (const float*)d_in[10];
  const float* W2     = (const float*)d_in[11];
  const float* b2     = (const float*)d_in[12];
  float* out = (float*)d_out;

  const int N = in_sizes[2];         // 50000
  const int E = in_sizes[1] / 2;     // 500000
  const int NL = in_sizes[6] / 128;  // 2 layers

  size_t off = 0;
  auto alloc = [&](size_t bytes) {
    void* p = (char*)d_ws + off;
    off += (bytes + 255) & ~(size_t)255;
    return p;
  };
  float* bufA   = (float*)alloc((size_t)N * 128 * 4);
  float* bufB   = (float*)alloc((size_t)N * 128 * 4);
  int*   deg    = (int*)alloc((size_t)N * 4);
  float* dinv   = (float*)alloc((size_t)N * 4);
  int*   rowptr = (int*)alloc((size_t)(N + 1) * 4);
  int*   cursor = (int*)alloc((size_t)N * 4);
  int*   colx   = (int*)alloc((size_t)(E + N) * 4);
  int*   blksum = (int*)alloc(1024 * 4);
  float* bnstat = (float*)alloc(512 * 4);
  float* scsh   = (float*)alloc(256 * 4);
  float* pooled = (float*)alloc(64 * 128 * 4);
  int*   gstart = (int*)alloc(65 * 4);

  int nbN = (N + 255) / 256;

  k_init<<<nbN, 256, 0, stream>>>(deg, pooled, bnstat, N);
  k_deg<<<(E + 255) / 256, 256, 0, stream>>>(ei, E, deg);
  k_scan_a<<<nbN, 256, 0, stream>>>(deg, N, rowptr, blksum);
  k_scan_b<<<1, 256, 0, stream>>>(blksum, nbN);
  k_scan_c<<<(N + 1 + 255) / 256, 256, 0, stream>>>(deg, N, E + N, blksum,
                                                    rowptr, cursor, dinv);
  k_fill<<<(E + N + 255) / 256, 256, 0, stream>>>(ei, E, N, cursor, colx);

  int gemmGrid = (N + 31) / 32;
  k_gemm<64><<<gemmGrid, 256, 0, stream>>>(x, W_enc, b_enc, nullptr, bufA, N);

  for (int l = 0; l < NL; l++) {
    k_gemm<128><<<gemmGrid, 256, 0, stream>>>(bufA, Wc + (size_t)l * 128 * 128,
                                              nullptr, dinv, bufB, N);
    k_agg<<<2048, 256, 0, stream>>>(bufB, rowptr, colx, dinv, bc + l * 128,
                                    bufA, N);
    k_bnstat<<<512, 256, 0, stream>>>(bufA, N, bnstat + l * 256);
    k_bnfinal<<<1, 128, 0, stream>>>(bnstat + l * 256, gamma + l * 128,
                                     beta + l * 128, 1.f / (float)N, scsh);
    k_bnapply<<<2048, 256, 0, stream>>>(bufA, N * 32, scsh);
  }

  k_gstart<<<1, 128, 0, stream>>>(batch, N, gstart);
  k_pool<<<256, 128, 0, stream>>>(bufA, gstart, pooled);
  k_mlp<<<1, 256, 0, stream>>>(pooled, gstart, W1, b1, W2, b2, out);
}